// Round 13
// baseline (702.477 us; speedup 1.0000x reference)
//
#include <hip/hip_runtime.h>

typedef _Float16 half_t;
typedef _Float16 half8 __attribute__((ext_vector_type(8)));
typedef _Float16 half4v __attribute__((ext_vector_type(4)));
typedef float floatx4 __attribute__((ext_vector_type(4)));

#define MFMA(a,b,c) __builtin_amdgcn_mfma_f32_16x16x32_f16(a,b,c,0,0,0)

#define NB 16
#define NLEN 1024
#define DD 128
#define BN (NB*NLEN)                       // 16384 rows per branch
#define BND ((size_t)NB*NLEN*DD)
#define BNN ((size_t)NB*NLEN*NLEN)
#define ELLS 128                           // ELL stride (max nnz/row ~99)
#define EMP 1044                           // emS row stride (bank-conflict-free)

static __device__ inline float f16lo(unsigned pk) {
    unsigned short us = (unsigned short)(pk & 0xffffu);
    half_t h; __builtin_memcpy(&h, &us, 2); return (float)h;
}
static __device__ inline half_t f16h(unsigned pk) {
    unsigned short us = (unsigned short)(pk & 0xffffu);
    half_t h; __builtin_memcpy(&h, &us, 2); return h;
}

// ---------------- prep: embed (blocks 0..2047) + weight casts (blocks 2048..2303)
__global__ __launch_bounds__(256)
void k_prep(const float* __restrict__ x, const float* __restrict__ Ew, half_t* __restrict__ h16,
            const float* __restrict__ gW, const float* __restrict__ gA,
            half_t* __restrict__ Wf, half_t* __restrict__ STf) {
    int tid = threadIdx.x;
    if (blockIdx.x >= 2048) {
        int i = (blockIdx.x - 2048) * 256 + tid;
        Wf[i] = (half_t)gW[i];
        int base = i & ~16383;
        int lrem = i & 16383;
        int d = lrem >> 7, e = lrem & 127;
        STf[base + (e << 7) + d] = (half_t)(gA[i] + gA[base + (e << 7) + d]);
        return;
    }
    __shared__ float rows[8][DD];
    int g = blockIdx.x * 8;
    {
        int nl = tid >> 5, c4 = (tid & 31) * 4;
        *(float4*)&rows[nl][c4] = *(const float4*)&x[(size_t)(g + nl) * DD + c4];
    }
    __syncthreads();
    int t = tid & 127, half = tid >> 7;
    const float* wr = Ew + (size_t)t * DD;
    float acc[4] = {0.f, 0.f, 0.f, 0.f};
    for (int k = 0; k < DD; k++) {
        float w = wr[k];
#pragma unroll
        for (int m = 0; m < 4; m++) acc[m] += rows[half + 2 * m][k] * w;
    }
#pragma unroll
    for (int m = 0; m < 4; m++) h16[(size_t)(g + half + 2 * m) * DD + t] = (half_t)acc[m];
}

// ---------------- ELL build (once): wave per row, ballot-based coalesced extraction.
// Slot order within a row is arbitrary (consumers are order-independent).
__global__ __launch_bounds__(256)
void k_ell(const float* __restrict__ adj1, const float* __restrict__ adj2,
           unsigned* __restrict__ ell, unsigned* __restrict__ cntA) {
    int t = threadIdx.x, w = t >> 6, l = t & 63;
    int R = blockIdx.x * 4 + w;
    int br = R >> 14, nb = R & 16383;
    const float* arow = (br ? adj2 : adj1) + (size_t)nb * 1024;
    unsigned* erow = ell + (size_t)R * ELLS;
    unsigned long long lmask = (l == 0) ? 0ull : (~0ull >> (64 - l));
    int base = 0;
#pragma unroll
    for (int ch = 0; ch < 4; ch++) {
        float4 v = *(const float4*)&arow[ch * 256 + l * 4];
        float vals[4] = {v.x, v.y, v.z, v.w};
#pragma unroll
        for (int comp = 0; comp < 4; comp++) {
            bool pred = vals[comp] > 0.f;
            unsigned long long b = __ballot(pred);
            if (pred) {
                int idx = base + __popcll(b & lmask);
                if (idx < ELLS) erow[idx] = ((unsigned)(ch * 256 + l * 4 + comp)) << 16;
            }
            base += __popcll(b);
        }
    }
    if (base > ELLS) base = ELLS;
    if (l == 0) cntA[R] = (unsigned)base;
    for (int s = base + l; s < ELLS; s += 64) erow[s] = 0u;
}

// ---------------- proj (MFMA): in = pa - pb (f16); hbr = in@W^T + b ; hS = hbr@S
// outputs: hbr16 row-major, hbrF/hSF in MFMA fragment order
__global__ __launch_bounds__(256)
void k_proj(const half_t* __restrict__ pa, const half_t* __restrict__ pb,
            const half_t* __restrict__ Wf, const float* __restrict__ bias,
            const half_t* __restrict__ STf,
            half_t* __restrict__ hbr16, half_t* __restrict__ hbrF, half_t* __restrict__ hSF) {
    __shared__ half_t htile[32 * 136];
    __shared__ half_t hbtile[32 * 136];
    int g = blockIdx.x * 32;
    int t = threadIdx.x;
    int w = t >> 6, l = t & 63, q = l >> 4, l15 = l & 15;
#pragma unroll
    for (int v = 0; v < 2; v++) {
        int idx = v * 256 + t; int r = idx >> 4, c8 = (idx & 15) * 8;
        half8 va = *(const half8*)&pa[((size_t)(g + r) << 7) + c8];
        if (pb) {
            half8 vb = *(const half8*)&pb[((size_t)(g + r) << 7) + c8];
            va = va - vb;
        }
        *(half8*)&htile[r * 136 + c8] = va;
    }
    __syncthreads();
    int rowh = (w & 1) * 16;
    int c0 = (w >> 1) * 4;
    half8 a1[4];
#pragma unroll
    for (int kc = 0; kc < 4; kc++) a1[kc] = *(const half8*)&htile[(rowh + l15) * 136 + kc * 32 + q * 8];
    floatx4 acc[4];
#pragma unroll
    for (int cc = 0; cc < 4; cc++) {
        int col = (c0 + cc) * 16 + l15;
        floatx4 a = {0.f, 0.f, 0.f, 0.f};
#pragma unroll
        for (int kc = 0; kc < 4; kc++) {
            half8 bf = *(const half8*)&Wf[((size_t)col << 7) + kc * 32 + q * 8];
            a = MFMA(a1[kc], bf, a);
        }
        float bv = bias[col];
        a.x += bv; a.y += bv; a.z += bv; a.w += bv;
        acc[cc] = a;
    }
#pragma unroll
    for (int cc = 0; cc < 4; cc++) {
        int col = (c0 + cc) * 16 + l15;
#pragma unroll
        for (int r = 0; r < 4; r++)
            hbtile[(rowh + q * 4 + r) * 136 + col] = (half_t)acc[cc][r];
    }
    __syncthreads();
    half8 a2[4];
#pragma unroll
    for (int kc = 0; kc < 4; kc++) a2[kc] = *(const half8*)&hbtile[(rowh + l15) * 136 + kc * 32 + q * 8];
#pragma unroll
    for (int cc = 0; cc < 4; cc++) {
        int col = (c0 + cc) * 16 + l15;
        floatx4 a = {0.f, 0.f, 0.f, 0.f};
#pragma unroll
        for (int kc = 0; kc < 4; kc++) {
            half8 bf = *(const half8*)&STf[((size_t)col << 7) + kc * 32 + q * 8];
            a = MFMA(a2[kc], bf, a);
        }
        acc[cc] = a;
    }
    __syncthreads();
#pragma unroll
    for (int cc = 0; cc < 4; cc++) {
        int col = (c0 + cc) * 16 + l15;
#pragma unroll
        for (int r = 0; r < 4; r++) htile[(rowh + q * 4 + r) * 136 + col] = (half_t)acc[cc][r];
    }
    __syncthreads();
#pragma unroll
    for (int v = 0; v < 2; v++) {
        int idx = v * 256 + t; int r = idx >> 4, c8 = (idx & 15) * 8;
        *(half8*)&hbr16[((size_t)(g + r) << 7) + c8] = *(const half8*)&hbtile[r * 136 + c8];
    }
#pragma unroll
    for (int v = 0; v < 2; v++) {
        int fi = v * 256 + t;
        int g2 = fi >> 8, kc = (fi >> 6) & 3, li = fi & 63;
        int src = (g2 * 16 + (li & 15)) * 136 + kc * 32 + (li >> 4) * 8;
        size_t dst = (((size_t)(blockIdx.x * 2 + g2) * 4 + kc) << 10) + li * 8;
        *(half8*)&hbrF[dst] = *(const half8*)&hbtile[src];
        *(half8*)&hSF[dst]  = *(const half8*)&htile[src];
    }
}

// ---------------- sparse E (unchanged)
__global__ __launch_bounds__(256)
void k_E(const half_t* __restrict__ hSF, const half_t* __restrict__ hbrF,
         const half_t* __restrict__ hbr16,
         unsigned* __restrict__ ell, const unsigned* __restrict__ cntA,
         float* __restrict__ rsr, half_t* __restrict__ hbrs) {
    int b = blockIdx.y, s = blockIdx.x;        // 64 strips of 16 rows
    int t = threadIdx.x, w = t >> 6, l = t & 63, q = l >> 4, l15 = l & 15;
    __shared__ half_t emS[16 * EMP];
    __shared__ float rsS[2][16];
    size_t Gb = (size_t)b * 64;
    half8 A[4];
#pragma unroll
    for (int kc = 0; kc < 4; kc++)
        A[kc] = *(const half8*)&hSF[(((Gb + s) * 4 + kc) << 10) + l * 8];
#pragma unroll 4
    for (int cg = 0; cg < 16; cg++) {
        int c0 = w * 256 + cg * 16;
        floatx4 a = {0.f, 0.f, 0.f, 0.f};
#pragma unroll
        for (int kc = 0; kc < 4; kc++) {
            half8 bf = *(const half8*)&hbrF[(((Gb + w * 16 + cg) * 4 + kc) << 10) + l * 8];
            a = MFMA(A[kc], bf, a);
        }
#pragma unroll
        for (int r = 0; r < 4; r++)
            emS[(q * 4 + r) * EMP + c0 + l15] = (half_t)a[r];
    }
    __syncthreads();
    const float CN = 0.000335462627903f;       // exp(-8)
#pragma unroll
    for (int rr = 0; rr < 4; rr++) {
        int rl = w * 4 + rr;
        int rowg = b * 1024 + s * 16 + rl;
#pragma unroll
        for (int br = 0; br < 2; br++) {
            size_t R = ((size_t)br << 14) + rowg;
            int cn = (int)cntA[R];
            float rs = 0.f;
            for (int base = 0; base < cn; base += 64) {
                int si = base + l;
                float v = 0.f;
                if (si < cn) {
                    unsigned pk = ell[R * ELLS + si];
                    int col = (int)(pk >> 16);
                    float em = (float)emS[rl * EMP + col];
                    v = __expf(em - 8.f);
                    half_t hv = (half_t)v;
                    unsigned short us; __builtin_memcpy(&us, &hv, 2);
                    ((unsigned short*)ell)[(R * ELLS + si) * 2] = us;
                }
                rs += v;
            }
            rs += __shfl_xor(rs, 1); rs += __shfl_xor(rs, 2);
            rs += __shfl_xor(rs, 4); rs += __shfl_xor(rs, 8);
            rs += __shfl_xor(rs, 16); rs += __shfl_xor(rs, 32);
            if (l == 0) {
                float rv = 1.f / (rs + (1024.f - (float)cn) * CN);
                rsr[R] = rv;
                rsS[br][rl] = rv;
            }
        }
    }
    __syncthreads();
    const half_t* hrow = hbr16 + ((size_t)b << 17) + ((size_t)(s * 16) << 7);
#pragma unroll
    for (int v = 0; v < 2; v++) {
        int idx = v * 256 + t;
        int row = idx >> 5, br2 = (idx >> 4) & 1, ch = idx & 15;
        half8 hv = *(const half8*)&hrow[(size_t)row * 128 + ch * 8];
        float sc = rsS[br2][row];
        half8 o;
#pragma unroll
        for (int d = 0; d < 8; d++) o[d] = (half_t)(sc * (float)hv[d]);
        *(half8*)&hbrs[(size_t)br2 * BND + ((size_t)(b * 1024 + s * 16 + row) << 7) + ch * 8] = o;
    }
}

// ---------------- sparse az + fused gate: 16 lanes/row, 8 dims/lane, 4 rows/wave.
// packed-f16 accumulation (v_pk_fma_f16): acc8 += zz * splat(val).
// mode1: blend w/ cfb, write rsr-scaled. mode2: blend w/ cfb, unscaled.
// mode3: compute cf in-kernel, write cfb, write rsr-scaled. mode4: compute cf, unscaled.
__global__ __launch_bounds__(256)
void k_az(const unsigned* __restrict__ ell, const unsigned* __restrict__ cntA,
          const float* __restrict__ rsr,
          const half_t* __restrict__ zin, const half_t* __restrict__ hbr16,
          const float* __restrict__ gw, const float* __restrict__ gb_,
          float* __restrict__ cfb, half_t* __restrict__ outp, int mode) {
    int t = threadIdx.x, w = t >> 6, l = t & 63;
    int g = l >> 4, l15 = l & 15;
    int R = blockIdx.x * 16 + w * 4 + g;
    int br = R >> 14, nb = R & 16383;
    const unsigned* ep = ell + (size_t)R * ELLS;
    int cn = (int)cntA[R];
    const half_t* zb = zin + (size_t)br * BND + (((size_t)(nb & ~1023)) << 7) + l15 * 8;
    half8 acc8 = {};
    for (int s = 0; s < cn; s += 4) {
        uint4 p4 = *(const uint4*)(ep + s);
        unsigned pk[4] = {p4.x, p4.y, p4.z, p4.w};
#pragma unroll
        for (int i = 0; i < 4; i++) {
            half8 zz = *(const half8*)(zb + (((size_t)(pk[i] >> 16)) << 7));
            half_t hv = f16h(pk[i]);
            half8 vv = {hv, hv, hv, hv, hv, hv, hv, hv};
            acc8 += zz * vv;
        }
    }
    float acc[8];
#pragma unroll
    for (int d = 0; d < 8; d++) acc[d] = fmaxf((float)acc8[d], 0.f);
    half8 hv8 = *(const half8*)&hbr16[((size_t)nb << 7) + l15 * 8];
    float hv[8];
#pragma unroll
    for (int d = 0; d < 8; d++) hv[d] = (float)hv8[d];
    float cf;
    if (mode >= 3) {
        const float* g1 = gw + l15 * 8;
        const float* g2 = gw + 128 + l15 * 8;
        float dp = 0.f;
#pragma unroll
        for (int d = 0; d < 8; d++) dp += hv[d] * g1[d] + acc[d] * g2[d];
        dp += __shfl_xor(dp, 1); dp += __shfl_xor(dp, 2);
        dp += __shfl_xor(dp, 4); dp += __shfl_xor(dp, 8);
        cf = 1.f / (1.f + __expf(-(dp + gb_[0])));
        if (l15 == 0) cfb[R] = cf;
    } else {
        cf = cfb[R];
    }
    float sc = (mode == 1 || mode == 3) ? rsr[R] : 1.f;
    half8 o;
#pragma unroll
    for (int d = 0; d < 8; d++)
        o[d] = (half_t)(sc * (cf * hv[d] + (1.f - cf) * acc[d]));
    *(half8*)&outp[(size_t)R * DD + l15 * 8] = o;
}

// ---------------- partial masked pool of (z2 - z1), f16 inputs
__global__ __launch_bounds__(256)
void k_pool(const half_t* __restrict__ z2, const half_t* __restrict__ z1,
            const float* __restrict__ valid, float* __restrict__ part) {
    int b = blockIdx.y, s = blockIdx.x;
    int t = threadIdx.x, d = t & 127, hf = t >> 7;
    __shared__ float red[128];
    float acc = 0.f;
    int nbase = s * 128 + hf * 64;
    for (int n = nbase; n < nbase + 64; n++) {
        size_t gi = ((size_t)(b * 1024 + n) << 7) + d;
        acc += ((float)z2[gi] - (float)z1[gi]) * valid[b * 1024 + n];
    }
    if (hf) red[d] = acc;
    __syncthreads();
    if (!hf) part[(b * 8 + s) * 128 + d] = acc + red[d];
}

// ---------------- final reduce + MLP head
__global__ __launch_bounds__(128)
void k_mlp(const float* __restrict__ part, const float* __restrict__ valid,
           const float* __restrict__ w0, const float* __restrict__ b0,
           const float* __restrict__ w1, const float* __restrict__ b1,
           const float* __restrict__ w2, const float* __restrict__ b2,
           const float* __restrict__ w3, const float* __restrict__ b3,
           float* __restrict__ out) {
    int b = blockIdx.x, t = threadIdx.x;
    __shared__ float y0[DD], y1[DD];
    __shared__ float sred[2];
    float vs = 0.f;
    for (int n = t; n < NLEN; n += 128) vs += valid[b * NLEN + n];
    for (int off = 32; off; off >>= 1) vs += __shfl_down(vs, off);
    if ((t & 63) == 0) sred[t >> 6] = vs;
    __syncthreads();
    float vsum = sred[0] + sred[1];
    float acc = 0.f;
#pragma unroll
    for (int s = 0; s < 8; s++) acc += part[(b * 8 + s) * 128 + t];
    y0[t] = acc / vsum;
    __syncthreads();
    float a = b0[t];
    for (int k = 0; k < DD; k++) a += y0[k] * w0[t * DD + k];
    y1[t] = fmaxf(a, 0.f);
    __syncthreads();
    a = b1[t];
    for (int k = 0; k < DD; k++) a += y1[k] * w1[t * DD + k];
    y0[t] = fmaxf(a, 0.f);
    __syncthreads();
    a = b2[t];
    for (int k = 0; k < DD; k++) a += y0[k] * w2[t * DD + k];
    y1[t] = fmaxf(a, 0.f);
    __syncthreads();
    float p = y1[t] * w3[t];
    for (int off = 32; off; off >>= 1) p += __shfl_down(p, off);
    if ((t & 63) == 0) sred[t >> 6] = p;
    __syncthreads();
    if (t == 0) out[b] = 1.f / (1.f + __expf(-(sred[0] + sred[1] + b3[0])));
}

extern "C" void kernel_launch(void* const* d_in, const int* in_sizes, int n_in,
                              void* d_out, int out_size, void* d_ws, size_t ws_size,
                              hipStream_t stream) {
    (void)in_sizes; (void)n_in; (void)out_size; (void)ws_size;
    const float* x     = (const float*)d_in[0];
    const float* adj1  = (const float*)d_in[1];
    const float* adj2  = (const float*)d_in[2];
    const float* valid = (const float*)d_in[3];
    const float* Ew    = (const float*)d_in[4];
    const float* gW    = (const float*)d_in[5];
    const float* gb    = (const float*)d_in[6];
    const float* gA    = (const float*)d_in[7];
    const float* gatew = (const float*)d_in[8];
    const float* gateb = (const float*)d_in[9];
    const float* w0 = (const float*)d_in[10]; const float* b0 = (const float*)d_in[11];
    const float* w1 = (const float*)d_in[12]; const float* b1 = (const float*)d_in[13];
    const float* w2 = (const float*)d_in[14]; const float* b2 = (const float*)d_in[15];
    const float* w3 = (const float*)d_in[16]; const float* b3 = (const float*)d_in[17];
    float* out = (float*)d_out;

    char* p = (char*)d_ws;
    float* rsr  = (float*)p; p += 2 * BN * 4;
    float* cfb  = (float*)p; p += 2 * BN * 4;
    float* partb = (float*)p; p += (size_t)NB * 8 * 128 * 4;
    half_t* h16   = (half_t*)p; p += BND * 2;
    half_t* hbr16 = (half_t*)p; p += BND * 2;
    half_t* hbrF  = (half_t*)p; p += BND * 2;
    half_t* hSF   = (half_t*)p; p += BND * 2;
    half_t* hbrs  = (half_t*)p; p += 2 * BND * 2;   // rsr-scaled hbr16 per branch
    half_t* zf    = (half_t*)p; p += 2 * BND * 2;   // layer outputs [br]
    half_t* zsA   = (half_t*)p; p += 2 * BND * 2;
    half_t* zsB   = (half_t*)p; p += 2 * BND * 2;
    unsigned* ell = (unsigned*)p; p += (size_t)2 * BN * ELLS * 4;
    unsigned* cntA = (unsigned*)p; p += (size_t)2 * BN * 4;
    half_t* Wf16 = (half_t*)p; p += (size_t)4 * 128 * 128 * 2;
    half_t* ST16 = (half_t*)p; p += (size_t)4 * 128 * 128 * 2;

    k_prep<<<2304, 256, 0, stream>>>(x, Ew, h16, gW, gA, Wf16, ST16);
    k_ell<<<8192, 256, 0, stream>>>(adj1, adj2, ell, cntA);

    for (int k = 0; k < 4; k++) {
        int nhop = k + 1;
        const half_t* pa = k ? (zf + BND) : h16;
        const half_t* pb = k ? zf : nullptr;
        k_proj<<<512, 256, 0, stream>>>(pa, pb, Wf16 + (size_t)k * 16384, gb + k * 128,
                                        ST16 + (size_t)k * 16384, hbr16, hbrF, hSF);
        k_E<<<dim3(64, NB), 256, 0, stream>>>(hSF, hbrF, hbr16, ell, cntA, rsr, hbrs);
        // hop 1 (gate fused): az from hbrs, cf computed in-kernel
        half_t* tgate = (nhop == 1) ? zf : zsA;
        k_az<<<2048, 256, 0, stream>>>(ell, cntA, rsr, hbrs, hbr16,
                                       gatew + k * 256, gateb + k, cfb, tgate,
                                       (nhop == 1) ? 4 : 3);
        half_t* src = tgate;
        for (int hop = 2; hop <= nhop; hop++) {
            half_t* dst = (hop == nhop) ? zf : ((hop & 1) ? zsA : zsB);
            k_az<<<2048, 256, 0, stream>>>(ell, cntA, rsr, src, hbr16,
                                           gatew + k * 256, gateb + k, cfb, dst,
                                           (hop == nhop) ? 2 : 1);
            src = dst;
        }
    }
    k_pool<<<dim3(8, NB), 256, 0, stream>>>(zf + BND, zf, valid, partb);
    k_mlp<<<16, 128, 0, stream>>>(partb, valid, w0, b0, w1, b1, w2, b2, w3, b3, out);
}

// Round 14
// 697.431 us; speedup vs baseline: 1.0072x; 1.0072x over previous
//
#include <hip/hip_runtime.h>

typedef _Float16 half_t;
typedef _Float16 half8 __attribute__((ext_vector_type(8)));
typedef _Float16 half4v __attribute__((ext_vector_type(4)));
typedef float floatx4 __attribute__((ext_vector_type(4)));

#define MFMA(a,b,c) __builtin_amdgcn_mfma_f32_16x16x32_f16(a,b,c,0,0,0)

#define NB 16
#define NLEN 1024
#define DD 128
#define BN (NB*NLEN)                       // 16384 rows per branch
#define BND ((size_t)NB*NLEN*DD)
#define BNN ((size_t)NB*NLEN*NLEN)
#define ELLS 128                           // ELL stride (max nnz/row ~99)
#define EMP 1044                           // emS row stride (bank-conflict-free)

static __device__ inline half_t f16h(unsigned pk) {
    unsigned short us = (unsigned short)(pk & 0xffffu);
    half_t h; __builtin_memcpy(&h, &us, 2); return h;
}

// ---------------- fused prologue:
// blocks 0..8191: ELL build (4 rows/block, ballot + LDS-staged coalesced store)
// blocks 8192..10239: embed h16 = f16(x @ Ew^T)
// blocks 10240..10495: weight casts
__global__ __launch_bounds__(256)
void k_pre(const float* __restrict__ adj1, const float* __restrict__ adj2,
           unsigned* __restrict__ ell, unsigned* __restrict__ cntA,
           const float* __restrict__ x, const float* __restrict__ Ew, half_t* __restrict__ h16,
           const float* __restrict__ gW, const float* __restrict__ gA,
           half_t* __restrict__ Wf, half_t* __restrict__ STf) {
    int tid = threadIdx.x;
    int bid = blockIdx.x;
    if (bid < 8192) {
        __shared__ unsigned ebuf[4][ELLS];
        int w = tid >> 6, l = tid & 63;
        int R = bid * 4 + w;
        int br = R >> 14, nb = R & 16383;
        const float* arow = (br ? adj2 : adj1) + (size_t)nb * 1024;
        unsigned* myb = ebuf[w];
        myb[l] = 0u; myb[l + 64] = 0u;          // wave-synchronous zero
        float4 v0 = *(const float4*)&arow[l * 4];
        float4 v1 = *(const float4*)&arow[256 + l * 4];
        float4 v2 = *(const float4*)&arow[512 + l * 4];
        float4 v3 = *(const float4*)&arow[768 + l * 4];
        unsigned long long lmask = (l == 0) ? 0ull : (~0ull >> (64 - l));
        int base = 0;
        float vals[16] = {v0.x, v0.y, v0.z, v0.w, v1.x, v1.y, v1.z, v1.w,
                          v2.x, v2.y, v2.z, v2.w, v3.x, v3.y, v3.z, v3.w};
#pragma unroll
        for (int ch = 0; ch < 4; ch++) {
#pragma unroll
            for (int comp = 0; comp < 4; comp++) {
                bool pred = vals[ch * 4 + comp] > 0.f;
                unsigned long long b = __ballot(pred);
                if (pred) {
                    int idx = base + __popcll(b & lmask);
                    if (idx < ELLS) myb[idx] = ((unsigned)(ch * 256 + l * 4 + comp)) << 16;
                }
                base += __popcll(b);
            }
        }
        if (base > ELLS) base = ELLS;
        if (l == 0) cntA[R] = (unsigned)base;
        uint2 o = {myb[l * 2], myb[l * 2 + 1]};
        *(uint2*)&ell[(size_t)R * ELLS + l * 2] = o;
        return;
    }
    if (bid >= 10240) {
        int i = (bid - 10240) * 256 + tid;
        Wf[i] = (half_t)gW[i];
        int base = i & ~16383;
        int lrem = i & 16383;
        int d = lrem >> 7, e = lrem & 127;
        STf[base + (e << 7) + d] = (half_t)(gA[i] + gA[base + (e << 7) + d]);
        return;
    }
    __shared__ float rows[8][DD];
    int g = (bid - 8192) * 8;
    {
        int nl = tid >> 5, c4 = (tid & 31) * 4;
        *(float4*)&rows[nl][c4] = *(const float4*)&x[(size_t)(g + nl) * DD + c4];
    }
    __syncthreads();
    int t = tid & 127, half = tid >> 7;
    const float* wr = Ew + (size_t)t * DD;
    float acc[4] = {0.f, 0.f, 0.f, 0.f};
    for (int k = 0; k < DD; k++) {
        float w = wr[k];
#pragma unroll
        for (int m = 0; m < 4; m++) acc[m] += rows[half + 2 * m][k] * w;
    }
#pragma unroll
    for (int m = 0; m < 4; m++) h16[(size_t)(g + half + 2 * m) * DD + t] = (half_t)acc[m];
}

// ---------------- proj (MFMA): in = pa - pb (f16); hbr = in@W^T + b ; hS = hbr@S
// outputs: hbr16 row-major, hbrF/hSF in MFMA fragment order
__global__ __launch_bounds__(256)
void k_proj(const half_t* __restrict__ pa, const half_t* __restrict__ pb,
            const half_t* __restrict__ Wf, const float* __restrict__ bias,
            const half_t* __restrict__ STf,
            half_t* __restrict__ hbr16, half_t* __restrict__ hbrF, half_t* __restrict__ hSF) {
    __shared__ half_t htile[32 * 136];
    __shared__ half_t hbtile[32 * 136];
    int g = blockIdx.x * 32;
    int t = threadIdx.x;
    int w = t >> 6, l = t & 63, q = l >> 4, l15 = l & 15;
#pragma unroll
    for (int v = 0; v < 2; v++) {
        int idx = v * 256 + t; int r = idx >> 4, c8 = (idx & 15) * 8;
        half8 va = *(const half8*)&pa[((size_t)(g + r) << 7) + c8];
        if (pb) {
            half8 vb = *(const half8*)&pb[((size_t)(g + r) << 7) + c8];
            va = va - vb;
        }
        *(half8*)&htile[r * 136 + c8] = va;
    }
    __syncthreads();
    int rowh = (w & 1) * 16;
    int c0 = (w >> 1) * 4;
    half8 a1[4];
#pragma unroll
    for (int kc = 0; kc < 4; kc++) a1[kc] = *(const half8*)&htile[(rowh + l15) * 136 + kc * 32 + q * 8];
    floatx4 acc[4];
#pragma unroll
    for (int cc = 0; cc < 4; cc++) {
        int col = (c0 + cc) * 16 + l15;
        floatx4 a = {0.f, 0.f, 0.f, 0.f};
#pragma unroll
        for (int kc = 0; kc < 4; kc++) {
            half8 bf = *(const half8*)&Wf[((size_t)col << 7) + kc * 32 + q * 8];
            a = MFMA(a1[kc], bf, a);
        }
        float bv = bias[col];
        a.x += bv; a.y += bv; a.z += bv; a.w += bv;
        acc[cc] = a;
    }
#pragma unroll
    for (int cc = 0; cc < 4; cc++) {
        int col = (c0 + cc) * 16 + l15;
#pragma unroll
        for (int r = 0; r < 4; r++)
            hbtile[(rowh + q * 4 + r) * 136 + col] = (half_t)acc[cc][r];
    }
    __syncthreads();
    half8 a2[4];
#pragma unroll
    for (int kc = 0; kc < 4; kc++) a2[kc] = *(const half8*)&hbtile[(rowh + l15) * 136 + kc * 32 + q * 8];
#pragma unroll
    for (int cc = 0; cc < 4; cc++) {
        int col = (c0 + cc) * 16 + l15;
        floatx4 a = {0.f, 0.f, 0.f, 0.f};
#pragma unroll
        for (int kc = 0; kc < 4; kc++) {
            half8 bf = *(const half8*)&STf[((size_t)col << 7) + kc * 32 + q * 8];
            a = MFMA(a2[kc], bf, a);
        }
        acc[cc] = a;
    }
    __syncthreads();
#pragma unroll
    for (int cc = 0; cc < 4; cc++) {
        int col = (c0 + cc) * 16 + l15;
#pragma unroll
        for (int r = 0; r < 4; r++) htile[(rowh + q * 4 + r) * 136 + col] = (half_t)acc[cc][r];
    }
    __syncthreads();
#pragma unroll
    for (int v = 0; v < 2; v++) {
        int idx = v * 256 + t; int r = idx >> 4, c8 = (idx & 15) * 8;
        *(half8*)&hbr16[((size_t)(g + r) << 7) + c8] = *(const half8*)&hbtile[r * 136 + c8];
    }
#pragma unroll
    for (int v = 0; v < 2; v++) {
        int fi = v * 256 + t;
        int g2 = fi >> 8, kc = (fi >> 6) & 3, li = fi & 63;
        int src = (g2 * 16 + (li & 15)) * 136 + kc * 32 + (li >> 4) * 8;
        size_t dst = (((size_t)(blockIdx.x * 2 + g2) * 4 + kc) << 10) + li * 8;
        *(half8*)&hbrF[dst] = *(const half8*)&hbtile[src];
        *(half8*)&hSF[dst]  = *(const half8*)&htile[src];
    }
}

// ---------------- sparse E (unchanged)
__global__ __launch_bounds__(256)
void k_E(const half_t* __restrict__ hSF, const half_t* __restrict__ hbrF,
         const half_t* __restrict__ hbr16,
         unsigned* __restrict__ ell, const unsigned* __restrict__ cntA,
         float* __restrict__ rsr, half_t* __restrict__ hbrs) {
    int b = blockIdx.y, s = blockIdx.x;        // 64 strips of 16 rows
    int t = threadIdx.x, w = t >> 6, l = t & 63, q = l >> 4, l15 = l & 15;
    __shared__ half_t emS[16 * EMP];
    __shared__ float rsS[2][16];
    size_t Gb = (size_t)b * 64;
    half8 A[4];
#pragma unroll
    for (int kc = 0; kc < 4; kc++)
        A[kc] = *(const half8*)&hSF[(((Gb + s) * 4 + kc) << 10) + l * 8];
#pragma unroll 4
    for (int cg = 0; cg < 16; cg++) {
        int c0 = w * 256 + cg * 16;
        floatx4 a = {0.f, 0.f, 0.f, 0.f};
#pragma unroll
        for (int kc = 0; kc < 4; kc++) {
            half8 bf = *(const half8*)&hbrF[(((Gb + w * 16 + cg) * 4 + kc) << 10) + l * 8];
            a = MFMA(A[kc], bf, a);
        }
#pragma unroll
        for (int r = 0; r < 4; r++)
            emS[(q * 4 + r) * EMP + c0 + l15] = (half_t)a[r];
    }
    __syncthreads();
    const float CN = 0.000335462627903f;       // exp(-8)
#pragma unroll
    for (int rr = 0; rr < 4; rr++) {
        int rl = w * 4 + rr;
        int rowg = b * 1024 + s * 16 + rl;
#pragma unroll
        for (int br = 0; br < 2; br++) {
            size_t R = ((size_t)br << 14) + rowg;
            int cn = (int)cntA[R];
            float rs = 0.f;
            for (int base = 0; base < cn; base += 64) {
                int si = base + l;
                float v = 0.f;
                if (si < cn) {
                    unsigned pk = ell[R * ELLS + si];
                    int col = (int)(pk >> 16);
                    float em = (float)emS[rl * EMP + col];
                    v = __expf(em - 8.f);
                    half_t hv = (half_t)v;
                    unsigned short us; __builtin_memcpy(&us, &hv, 2);
                    ((unsigned short*)ell)[(R * ELLS + si) * 2] = us;
                }
                rs += v;
            }
            rs += __shfl_xor(rs, 1); rs += __shfl_xor(rs, 2);
            rs += __shfl_xor(rs, 4); rs += __shfl_xor(rs, 8);
            rs += __shfl_xor(rs, 16); rs += __shfl_xor(rs, 32);
            if (l == 0) {
                float rv = 1.f / (rs + (1024.f - (float)cn) * CN);
                rsr[R] = rv;
                rsS[br][rl] = rv;
            }
        }
    }
    __syncthreads();
    const half_t* hrow = hbr16 + ((size_t)b << 17) + ((size_t)(s * 16) << 7);
#pragma unroll
    for (int v = 0; v < 2; v++) {
        int idx = v * 256 + t;
        int row = idx >> 5, br2 = (idx >> 4) & 1, ch = idx & 15;
        half8 hv = *(const half8*)&hrow[(size_t)row * 128 + ch * 8];
        float sc = rsS[br2][row];
        half8 o;
#pragma unroll
        for (int d = 0; d < 8; d++) o[d] = (half_t)(sc * (float)hv[d]);
        *(half8*)&hbrs[(size_t)br2 * BND + ((size_t)(b * 1024 + s * 16 + row) << 7) + ch * 8] = o;
    }
}

// ---------------- sparse az + fused gate: 16 lanes/row, 8 dims/lane, 4 rows/wave.
// packed-f16 accumulation + rotating entry prefetch.
// mode1: blend w/ cfb, rsr-scaled. mode2: blend, unscaled.
// mode3: compute cf in-kernel, rsr-scaled. mode4: compute cf, unscaled.
__global__ __launch_bounds__(256)
void k_az(const unsigned* __restrict__ ell, const unsigned* __restrict__ cntA,
          const float* __restrict__ rsr,
          const half_t* __restrict__ zin, const half_t* __restrict__ hbr16,
          const float* __restrict__ gw, const float* __restrict__ gb_,
          float* __restrict__ cfb, half_t* __restrict__ outp, int mode) {
    int t = threadIdx.x, w = t >> 6, l = t & 63;
    int g = l >> 4, l15 = l & 15;
    int R = blockIdx.x * 16 + w * 4 + g;
    int br = R >> 14, nb = R & 16383;
    const unsigned* ep = ell + (size_t)R * ELLS;
    int cn = (int)cntA[R];
    const half_t* zb = zin + (size_t)br * BND + (((size_t)(nb & ~1023)) << 7) + l15 * 8;
    half8 acc8 = {};
    uint4 p4 = *(const uint4*)ep;
    for (int s = 0; s < cn; s += 4) {
        uint4 cur = p4;
        p4 = *(const uint4*)(ep + s + 4);      // 16B slack appended to ell
        unsigned pk[4] = {cur.x, cur.y, cur.z, cur.w};
#pragma unroll
        for (int i = 0; i < 4; i++) {
            half8 zz = *(const half8*)(zb + (((size_t)(pk[i] >> 16)) << 7));
            half_t hv = f16h(pk[i]);
            half8 vv = {hv, hv, hv, hv, hv, hv, hv, hv};
            acc8 += zz * vv;
        }
    }
    float acc[8];
#pragma unroll
    for (int d = 0; d < 8; d++) acc[d] = fmaxf((float)acc8[d], 0.f);
    half8 hv8 = *(const half8*)&hbr16[((size_t)nb << 7) + l15 * 8];
    float hv[8];
#pragma unroll
    for (int d = 0; d < 8; d++) hv[d] = (float)hv8[d];
    float cf;
    if (mode >= 3) {
        const float* g1 = gw + l15 * 8;
        const float* g2 = gw + 128 + l15 * 8;
        float dp = 0.f;
#pragma unroll
        for (int d = 0; d < 8; d++) dp += hv[d] * g1[d] + acc[d] * g2[d];
        dp += __shfl_xor(dp, 1); dp += __shfl_xor(dp, 2);
        dp += __shfl_xor(dp, 4); dp += __shfl_xor(dp, 8);
        cf = 1.f / (1.f + __expf(-(dp + gb_[0])));
        if (l15 == 0) cfb[R] = cf;
    } else {
        cf = cfb[R];
    }
    float sc = (mode == 1 || mode == 3) ? rsr[R] : 1.f;
    half8 o;
#pragma unroll
    for (int d = 0; d < 8; d++)
        o[d] = (half_t)(sc * (cf * hv[d] + (1.f - cf) * acc[d]));
    *(half8*)&outp[(size_t)R * DD + l15 * 8] = o;
}

// ---------------- partial masked pool of (z2 - z1), f16 inputs
__global__ __launch_bounds__(256)
void k_pool(const half_t* __restrict__ z2, const half_t* __restrict__ z1,
            const float* __restrict__ valid, float* __restrict__ part) {
    int b = blockIdx.y, s = blockIdx.x;
    int t = threadIdx.x, d = t & 127, hf = t >> 7;
    __shared__ float red[128];
    float acc = 0.f;
    int nbase = s * 128 + hf * 64;
    for (int n = nbase; n < nbase + 64; n++) {
        size_t gi = ((size_t)(b * 1024 + n) << 7) + d;
        acc += ((float)z2[gi] - (float)z1[gi]) * valid[b * 1024 + n];
    }
    if (hf) red[d] = acc;
    __syncthreads();
    if (!hf) part[(b * 8 + s) * 128 + d] = acc + red[d];
}

// ---------------- final reduce + MLP head
__global__ __launch_bounds__(128)
void k_mlp(const float* __restrict__ part, const float* __restrict__ valid,
           const float* __restrict__ w0, const float* __restrict__ b0,
           const float* __restrict__ w1, const float* __restrict__ b1,
           const float* __restrict__ w2, const float* __restrict__ b2,
           const float* __restrict__ w3, const float* __restrict__ b3,
           float* __restrict__ out) {
    int b = blockIdx.x, t = threadIdx.x;
    __shared__ float y0[DD], y1[DD];
    __shared__ float sred[2];
    float vs = 0.f;
    for (int n = t; n < NLEN; n += 128) vs += valid[b * NLEN + n];
    for (int off = 32; off; off >>= 1) vs += __shfl_down(vs, off);
    if ((t & 63) == 0) sred[t >> 6] = vs;
    __syncthreads();
    float vsum = sred[0] + sred[1];
    float acc = 0.f;
#pragma unroll
    for (int s = 0; s < 8; s++) acc += part[(b * 8 + s) * 128 + t];
    y0[t] = acc / vsum;
    __syncthreads();
    float a = b0[t];
    for (int k = 0; k < DD; k++) a += y0[k] * w0[t * DD + k];
    y1[t] = fmaxf(a, 0.f);
    __syncthreads();
    a = b1[t];
    for (int k = 0; k < DD; k++) a += y1[k] * w1[t * DD + k];
    y0[t] = fmaxf(a, 0.f);
    __syncthreads();
    a = b2[t];
    for (int k = 0; k < DD; k++) a += y0[k] * w2[t * DD + k];
    y1[t] = fmaxf(a, 0.f);
    __syncthreads();
    float p = y1[t] * w3[t];
    for (int off = 32; off; off >>= 1) p += __shfl_down(p, off);
    if ((t & 63) == 0) sred[t >> 6] = p;
    __syncthreads();
    if (t == 0) out[b] = 1.f / (1.f + __expf(-(sred[0] + sred[1] + b3[0])));
}

extern "C" void kernel_launch(void* const* d_in, const int* in_sizes, int n_in,
                              void* d_out, int out_size, void* d_ws, size_t ws_size,
                              hipStream_t stream) {
    (void)in_sizes; (void)n_in; (void)out_size; (void)ws_size;
    const float* x     = (const float*)d_in[0];
    const float* adj1  = (const float*)d_in[1];
    const float* adj2  = (const float*)d_in[2];
    const float* valid = (const float*)d_in[3];
    const float* Ew    = (const float*)d_in[4];
    const float* gW    = (const float*)d_in[5];
    const float* gb    = (const float*)d_in[6];
    const float* gA    = (const float*)d_in[7];
    const float* gatew = (const float*)d_in[8];
    const float* gateb = (const float*)d_in[9];
    const float* w0 = (const float*)d_in[10]; const float* b0 = (const float*)d_in[11];
    const float* w1 = (const float*)d_in[12]; const float* b1 = (const float*)d_in[13];
    const float* w2 = (const float*)d_in[14]; const float* b2 = (const float*)d_in[15];
    const float* w3 = (const float*)d_in[16]; const float* b3 = (const float*)d_in[17];
    float* out = (float*)d_out;

    char* p = (char*)d_ws;
    float* rsr  = (float*)p; p += 2 * BN * 4;
    float* cfb  = (float*)p; p += 2 * BN * 4;
    float* partb = (float*)p; p += (size_t)NB * 8 * 128 * 4;
    half_t* h16   = (half_t*)p; p += BND * 2;
    half_t* hbr16 = (half_t*)p; p += BND * 2;
    half_t* hbrF  = (half_t*)p; p += BND * 2;
    half_t* hSF   = (half_t*)p; p += BND * 2;
    half_t* hbrs  = (half_t*)p; p += 2 * BND * 2;   // rsr-scaled hbr16 per branch
    half_t* zf    = (half_t*)p; p += 2 * BND * 2;   // layer outputs [br]
    half_t* zsA   = (half_t*)p; p += 2 * BND * 2;
    half_t* zsB   = (half_t*)p; p += 2 * BND * 2;
    unsigned* ell = (unsigned*)p; p += (size_t)2 * BN * ELLS * 4 + 16;  // +16B prefetch slack
    unsigned* cntA = (unsigned*)p; p += (size_t)2 * BN * 4;
    half_t* Wf16 = (half_t*)p; p += (size_t)4 * 128 * 128 * 2;
    half_t* ST16 = (half_t*)p; p += (size_t)4 * 128 * 128 * 2;

    k_pre<<<10496, 256, 0, stream>>>(adj1, adj2, ell, cntA, x, Ew, h16, gW, gA, Wf16, ST16);

    for (int k = 0; k < 4; k++) {
        int nhop = k + 1;
        const half_t* pa = k ? (zf + BND) : h16;
        const half_t* pb = k ? zf : nullptr;
        k_proj<<<512, 256, 0, stream>>>(pa, pb, Wf16 + (size_t)k * 16384, gb + k * 128,
                                        ST16 + (size_t)k * 16384, hbr16, hbrF, hSF);
        k_E<<<dim3(64, NB), 256, 0, stream>>>(hSF, hbrF, hbr16, ell, cntA, rsr, hbrs);
        // hop 1 (gate fused): az from hbrs, cf computed in-kernel
        half_t* tgate = (nhop == 1) ? zf : zsA;
        k_az<<<2048, 256, 0, stream>>>(ell, cntA, rsr, hbrs, hbr16,
                                       gatew + k * 256, gateb + k, cfb, tgate,
                                       (nhop == 1) ? 4 : 3);
        half_t* src = tgate;
        for (int hop = 2; hop <= nhop; hop++) {
            half_t* dst = (hop == nhop) ? zf : ((hop & 1) ? zsA : zsB);
            k_az<<<2048, 256, 0, stream>>>(ell, cntA, rsr, src, hbr16,
                                           gatew + k * 256, gateb + k, cfb, dst,
                                           (hop == nhop) ? 2 : 1);
            src = dst;
        }
    }
    k_pool<<<dim3(8, NB), 256, 0, stream>>>(zf + BND, zf, valid, partb);
    k_mlp<<<16, 128, 0, stream>>>(partb, valid, w0, b0, w1, b1, w2, b2, w3, b3, out);
}